// Round 14
// baseline (380.773 us; speedup 1.0000x reference)
//
#include <hip/hip_runtime.h>
#include <math.h>

#define ZB 16
#define NATOMS 192
#define NBAS 40
#define ZA (ZB*NATOMS)       // 3072
#define NKC 48               // K-chunks in contraction (768 blocks = 3/CU)

typedef __attribute__((ext_vector_type(4))) float f32x4;
typedef __attribute__((ext_vector_type(8))) short bf16x8;

__device__ __forceinline__ unsigned short f2bf(float x){
    union { float f; unsigned u; } v; v.f = x;
    unsigned r = v.u + 0x7FFFu + ((v.u >> 16) & 1u);
    return (unsigned short)(r >> 16);
}
// truncating bf16 (1 op) — hot paths
__device__ __forceinline__ unsigned short f2bf_t(float x){
    union { float f; unsigned u; } v; v.f = x;
    return (unsigned short)(v.u >> 16);
}
__device__ __forceinline__ float bf2f(unsigned short u){
    union { unsigned u; float f; } v; v.u = ((unsigned)u) << 16; return v.f;
}
__device__ __forceinline__ float bits2f(unsigned u){
    union { unsigned u; float f; } v; v.u = u; return v.f;
}
__device__ __forceinline__ unsigned f2bits(float x){
    union { float f; unsigned u; } v; v.f = x; return v.u;
}
// lean ssp: inputs bounded (|x| << 17) so no overflow guard needed
__device__ __forceinline__ float sspf_lean(float x){
    float e = __builtin_amdgcn_exp2f(7.2134752f*x);
    float l = __builtin_amdgcn_logf(1.f + e);
    return fmaf(l, 0.13862944f, -0.13862944f);
}
__device__ __forceinline__ float spf_act(float x){
    float t = 7.2134752f*x;
    float tc = fminf(t, 126.f);
    float e = __builtin_amdgcn_exp2f(tc);
    float l = __builtin_amdgcn_logf(1.f + e);
    float r = l*0.13862944f;
    return (t > 126.f) ? x : r;
}

// ---------------- prep: w2T[layer][hout*64+hin] = bf16(rW2[hin][hout]) and
// Bp[layer][(j*64+h)*64 + i] = bf16(rWo[h][j][i]) — both layers, one launch
__global__ void k_prep(const float* __restrict__ rW2_0, const float* __restrict__ rW2_1,
                       const float* __restrict__ rWo_0, const float* __restrict__ rWo_1,
                       unsigned short* __restrict__ w2T, unsigned short* __restrict__ Bp){
    int idx = blockIdx.x*256 + threadIdx.x;
    if (idx < 8192){
        int l = idx >> 12, r = idx & 4095;
        int hout = r >> 6, hin = r & 63;
        const float* src = l ? rW2_1 : rW2_0;
        w2T[idx] = f2bf(src[hin*64 + hout]);
    }
    for (int i = idx; i < 2*262144; i += gridDim.x*256){
        int l = i >> 18, r = i & 262143;
        int n = r >> 6, ii = r & 63;       // n = j*64+h
        int j = n >> 6, h = n & 63;
        const float* src = l ? rWo_1 : rWo_0;
        Bp[i] = f2bf(src[(h*64 + j)*64 + ii]);
    }
}

// ---------------- tmp GEMM bf16 MFMA: Tg[m][s*4096 + j*64 + h] = (f_s[m] @ rWo[h][j][:]) * mask*c
// layer 0 (feat != null): f_s rows computed on the fly from the linear encoders.
__global__ __launch_bounds__(256,2) void k_tmpB(
    const unsigned short* __restrict__ fb, const unsigned short* __restrict__ fc,
    const float* __restrict__ feat,
    const float* __restrict__ Wb, const float* __restrict__ bb,
    const float* __restrict__ Wc, const float* __restrict__ bc,
    const float* __restrict__ mask, const unsigned short* __restrict__ Bp,
    unsigned short* __restrict__ Tg)
{
    __shared__ unsigned short sm[18432];   // As[128*72] | Bs[128*72]; Cs overlays all
    __shared__ float msk[128];
    __shared__ float featS[128*8];
    __shared__ float WbS[7*64];
    __shared__ float bbS[64], WcS[64], bcS[64];
    unsigned short* As = sm;
    unsigned short* Bs = sm + 9216;
    unsigned short* Cs = sm;

    int tid = threadIdx.x;
    int m0 = blockIdx.x*128, n0 = blockIdx.y*128, s = blockIdx.z;
    int lane = tid & 63, w = tid >> 6, q = lane >> 4, l15 = lane & 15;
    int wm = w & 1, wn = w >> 1;

    if (feat){
        #pragma unroll
        for (int it = 0; it < 4; it++){
            int idx = tid + it*256;            // 1024 floats
            featS[idx] = feat[(size_t)m0*8 + idx];
        }
        for (int i = tid; i < 448; i += 256) WbS[i] = Wb[i];   // 7x64, strided
        if (tid < 64){ bbS[tid] = bb[tid]; WcS[tid] = Wc[tid]; bcS[tid] = bc[tid]; }
        __syncthreads();
        #pragma unroll
        for (int it = 0; it < 32; it++){
            int idx = tid + it*256;            // 8192
            int r = idx >> 6, e = idx & 63;
            float acc;
            if (s == 0){
                acc = bbS[e];
                #pragma unroll
                for (int c = 0; c < 7; c++) acc += featS[r*8+c]*WbS[c*64+e];
            } else {
                acc = bcS[e] + featS[r*8+7]*WcS[e];
            }
            As[r*72 + e] = f2bf(acc);
        }
    } else {
        const unsigned short* f = s ? fc : fb;
        #pragma unroll
        for (int it = 0; it < 4; it++){
            int idx = tid + it*256;            // 1024 uint4
            int r = idx >> 3, c8 = idx & 7;
            *(uint4*)(As + r*72 + c8*8) = *(const uint4*)(f + (size_t)(m0 + r)*64 + c8*8);
        }
    }
    // B-staging: pure uint4 copies from pre-converted Bp rows
    #pragma unroll
    for (int it = 0; it < 4; it++){
        int idx = tid + it*256;                // 1024 uint4
        int r = idx >> 3, c8 = idx & 7;
        *(uint4*)(Bs + r*72 + c8*8) = *(const uint4*)(Bp + (size_t)(n0 + r)*64 + c8*8);
    }
    if (tid < 128) msk[tid] = mask[m0 + tid] * 0.07216878364870322f;
    __syncthreads();

    f32x4 acc[16];
    #pragma unroll
    for (int i = 0; i < 16; i++) acc[i] = (f32x4){0.f,0.f,0.f,0.f};
    #pragma unroll
    for (int kc = 0; kc < 2; kc++){
        bf16x8 af[4];
        #pragma unroll
        for (int mt = 0; mt < 4; mt++)
            af[mt] = *(const bf16x8*)(As + (wm*64 + mt*16 + l15)*72 + kc*32 + q*8);
        #pragma unroll
        for (int nt = 0; nt < 4; nt++){
            bf16x8 bf_ = *(const bf16x8*)(Bs + (wn*64 + nt*16 + l15)*72 + kc*32 + q*8);
            #pragma unroll
            for (int mt = 0; mt < 4; mt++)
                acc[mt*4+nt] = __builtin_amdgcn_mfma_f32_16x16x32_bf16(af[mt], bf_, acc[mt*4+nt], 0, 0, 0);
        }
    }
    __syncthreads();   // all As/Bs reads done -> overlay Cs
    #pragma unroll
    for (int mt = 0; mt < 4; mt++)
        #pragma unroll
        for (int nt = 0; nt < 4; nt++)
            #pragma unroll
            for (int e = 0; e < 4; e++){
                int row2 = mt*16 + q*4 + e;
                float v = acc[mt*4+nt][e] * msk[wm*64 + row2];
                Cs[w*4608 + row2*72 + nt*16 + l15] = f2bf_t(v);
            }
    __syncthreads();
    #pragma unroll
    for (int it = 0; it < 8; it++){
        int flat = lane + it*64;               // [0,512)
        int rr = flat >> 3, c8 = flat & 7;
        uint4 v = *(const uint4*)(Cs + w*4608 + rr*72 + c8*8);
        size_t dst = (size_t)(m0 + wm*64 + rr)*8192 + s*4096 + n0 + wn*64 + c8*8;
        *(uint4*)(Tg + dst) = v;
    }
}

// ---------------- FUSED radial + contraction. Grid (ZB, NKC=48), 4 b's per block.
// Single-buffered Tg tile -> 52.1 KB LDS -> 3 blocks/CU.
__global__ __launch_bounds__(256,3) void k_fused(
    const float* __restrict__ geom,
    const float* __restrict__ rW1, const float* __restrict__ rb1,
    const unsigned short* __restrict__ w2T, const float* __restrict__ rb2,
    const unsigned short* __restrict__ Tc,
    unsigned short* __restrict__ part)
{
    __shared__ unsigned short smH[192*72];      // 27648 B: R tile -> epilogue staging
    __shared__ unsigned short smB[128*72];      // 18432 B: Tg tile (single buffer)
    __shared__ unsigned short W1bf[NBAS*72];    // 5760 B, rows padded to 72
    __shared__ float rb2s[64];

    int tid = threadIdx.x;
    int z = blockIdx.x, kc = blockIdx.y;
    int lane = tid & 63, w = tid >> 6, q = lane >> 4, l15 = lane & 15;
    int a_r = tid >> 3, c8 = tid & 7;

    #pragma unroll
    for (int i = 0; i < 10; i++){
        int idx = tid + i*256;                 // [0,2560)
        int r = idx >> 6, c = idx & 63;
        W1bf[r*72 + c] = f2bf(rW1[idx]);
    }
    if (tid < 64) rb2s[tid] = rb2[tid];

    bf16x8 bfr[2][4];
    #pragma unroll
    for (int kq = 0; kq < 2; kq++)
        #pragma unroll
        for (int nt = 0; nt < 4; nt++)
            bfr[kq][nt] = *(const bf16x8*)(w2T + (nt*16 + l15)*64 + kq*32 + q*8);

    float rb1v[2][8];
    #pragma unroll
    for (int kq = 0; kq < 2; kq++){
        float4 t0 = *(const float4*)(rb1 + kq*32 + q*8);
        float4 t1 = *(const float4*)(rb1 + kq*32 + q*8 + 4);
        rb1v[kq][0]=t0.x; rb1v[kq][1]=t0.y; rb1v[kq][2]=t0.z; rb1v[kq][3]=t0.w;
        rb1v[kq][4]=t1.x; rb1v[kq][5]=t1.y; rb1v[kq][6]=t1.z; rb1v[kq][7]=t1.w;
    }

    float gaxr[3], gayr[3], gazr[3];
    #pragma unroll
    for (int mt = 0; mt < 3; mt++){
        int ar = w*48 + mt*16 + l15;
        const float* gp = geom + (size_t)(z*NATOMS + ar)*3;
        gaxr[mt] = gp[0]; gayr[mt] = gp[1]; gazr[mt] = gp[2];
    }

    const size_t Tbase = (size_t)z*NATOMS*8192;
    uint4 rbv[4];
    {
        const unsigned short* Bb = Tc + Tbase + (size_t)(kc*4)*8192;
        #pragma unroll
        for (int r = 0; r < 4; r++) rbv[r] = *(const uint4*)(Bb + (size_t)(a_r + 32*r)*64 + c8*8);
    }

    f32x4 acc[24];
    #pragma unroll
    for (int i = 0; i < 24; i++) acc[i] = (f32x4){0.f,0.f,0.f,0.f};

    __syncthreads();           // W1bf / rb2s staged

    for (int i = 0; i < 4; i++){
        int b = kc*4 + i;
        if (i) __syncthreads();     // prev contraction reads of smB done
        #pragma unroll
        for (int r = 0; r < 4; r++) *(uint4*)(smB + (a_r + 32*r)*72 + c8*8) = rbv[r];
        if (i < 3){
            const unsigned short* Bb = Tc + Tbase + (size_t)(b+1)*8192;
            #pragma unroll
            for (int r = 0; r < 4; r++) rbv[r] = *(const uint4*)(Bb + (size_t)(a_r + 32*r)*64 + c8*8);
        }
        const float* gb = geom + (size_t)(z*NATOMS + b)*3;
        float gbx = gb[0], gby = gb[1], gbz = gb[2];
        float c0r[3], c1r[3]; int o0r[3], o1r[3];
        #pragma unroll
        for (int mt = 0; mt < 3; mt++){
            float dx = gaxr[mt]-gbx, dy = gayr[mt]-gby, dz = gazr[mt]-gbz;
            float r = sqrtf(dx*dx + dy*dy + dz*dz);
            float u = r * 3.9f;
            int k0 = (int)u;
            float fr = u - (float)k0;
            float cs = __cosf(fr * 1.57079632679489662f);
            float c0 = cs*cs, c1 = 1.f - c0;
            if (k0   >= NBAS) c0 = 0.f;
            if (k0+1 >= NBAS) c1 = 0.f;
            c0r[mt] = c0; c1r[mt] = c1;
            o0r[mt] = min(k0, NBAS-1)*72;
            o1r[mt] = min(k0+1, NBAS-1)*72;
        }
        __syncthreads();       // smB visible to all waves
        f32x4 hacc[12];
        #pragma unroll
        for (int t = 0; t < 12; t++) hacc[t] = (f32x4){0.f,0.f,0.f,0.f};
        #pragma unroll
        for (int kq = 0; kq < 2; kq++){
            #pragma unroll
            for (int mt = 0; mt < 3; mt++){
                uint4 w0 = *(const uint4*)(W1bf + o0r[mt] + kq*32 + q*8);
                uint4 w1 = *(const uint4*)(W1bf + o1r[mt] + kq*32 + q*8);
                const unsigned* w0p = (const unsigned*)&w0;
                const unsigned* w1p = (const unsigned*)&w1;
                uint4 af_u;
                unsigned* ap = (unsigned*)&af_u;
                #pragma unroll
                for (int d = 0; d < 4; d++){
                    float a0 = bits2f(w0p[d] << 16);
                    float a1 = bits2f(w0p[d] & 0xffff0000u);
                    float b0 = bits2f(w1p[d] << 16);
                    float b1 = bits2f(w1p[d] & 0xffff0000u);
                    float v0 = fmaf(c1r[mt], b0, fmaf(c0r[mt], a0, rb1v[kq][2*d]));
                    float v1 = fmaf(c1r[mt], b1, fmaf(c0r[mt], a1, rb1v[kq][2*d+1]));
                    unsigned u0 = f2bits(sspf_lean(v0));
                    unsigned u1 = f2bits(sspf_lean(v1));
                    ap[d] = (u0 >> 16) | (u1 & 0xffff0000u);
                }
                bf16x8 af = *(bf16x8*)&af_u;
                #pragma unroll
                for (int nt = 0; nt < 4; nt++)
                    hacc[mt*4+nt] = __builtin_amdgcn_mfma_f32_16x16x32_bf16(af, bfr[kq][nt], hacc[mt*4+nt], 0, 0, 0);
            }
        }
        #pragma unroll
        for (int mt = 0; mt < 3; mt++)
            #pragma unroll
            for (int nt = 0; nt < 4; nt++){
                float b2 = rb2s[nt*16 + l15];
                #pragma unroll
                for (int e = 0; e < 4; e++){
                    int row = w*48 + mt*16 + q*4 + e;
                    smH[row*72 + nt*16 + l15] = f2bf_t(sspf_lean(hacc[mt*4+nt][e] + b2));
                }
            }
        #pragma unroll
        for (int kq = 0; kq < 2; kq++){
            bf16x8 af[3];
            #pragma unroll
            for (int mt = 0; mt < 3; mt++)
                af[mt] = *(const bf16x8*)(smH + (w*48 + mt*16 + l15)*72 + kq*32 + q*8);
            #pragma unroll
            for (int nt = 0; nt < 8; nt++){
                bf16x8 bb = *(const bf16x8*)(smB + (nt*16 + l15)*72 + kq*32 + q*8);
                #pragma unroll
                for (int mt = 0; mt < 3; mt++)
                    acc[mt*8+nt] = __builtin_amdgcn_mfma_f32_16x16x32_bf16(af[mt], bb, acc[mt*8+nt], 0, 0, 0);
            }
        }
    }
    // epilogue: LDS-staged contiguous write of part tile (192x128 bf16)
    unsigned short* stg = smH;               // row stride 136 shorts
    #pragma unroll
    for (int half = 0; half < 2; half++){
        __syncthreads();
        if ((w >> 1) == half){
            int wl = w & 1;
            #pragma unroll
            for (int mt = 0; mt < 3; mt++)
                #pragma unroll
                for (int nt = 0; nt < 8; nt++)
                    #pragma unroll
                    for (int e = 0; e < 4; e++){
                        int row = wl*48 + mt*16 + q*4 + e;      // [0,96)
                        stg[row*136 + nt*16 + l15] = f2bf_t(acc[mt*8+nt][e]);
                    }
        }
        __syncthreads();
        unsigned short* gdst = part + ((size_t)(z*NKC + kc)*NATOMS + half*96)*128;
        #pragma unroll
        for (int it = 0; it < 6; it++){
            int flat = tid + it*256;          // [0,1536) uint4s
            int row = flat >> 4, cc = flat & 15;
            uint4 v = *(const uint4*)(stg + row*136 + cc*8);
            *(uint4*)(gdst + row*128 + cc*8) = v;
        }
    }
}

// ---------------- reduce partials + sp + mask -> bf16 next features (layer 0 only)
__global__ void k_reduceB(const unsigned short* __restrict__ part, const float* __restrict__ mask,
                          unsigned short* __restrict__ fb, unsigned short* __restrict__ fc){
    int zl = blockIdx.y;
    int idx = blockIdx.x*256 + threadIdx.x;    // [0, 24576)
    int a = idx >> 7, j2 = idx & 127;
    const unsigned short* p = part + ((size_t)(zl*NKC)*NATOMS + a)*128 + j2;
    float s = 0.f;
    #pragma unroll
    for (int c = 0; c < NKC; c++) s += bf2f(p[(size_t)c*NATOMS*128]);
    int rowg = zl*NATOMS + a;
    float v = spf_act(s) * mask[rowg];
    if (j2 < 64) fb[rowg*64 + j2] = f2bf(v);
    else         fc[rowg*64 + j2 - 64] = f2bf(v);
}

// ---------------- fused tail: reduce(layer1) + sp + mask + h1 + BN1 + leaky + h2 + BN2
// + leaky + mask + atom-sum (atomicAdd into zeroed out). One block per atom.
__global__ __launch_bounds__(256) void k_head2(
    const unsigned short* __restrict__ part, const float* __restrict__ mask,
    const float* __restrict__ fW1, const float* __restrict__ fb1,
    const float* __restrict__ fW2, const float* __restrict__ fb2,
    float* __restrict__ out)
{
    __shared__ float X[2048];
    __shared__ float red[16];
    __shared__ float stats[2];
    int a = blockIdx.x, tid = threadIdx.x;
    int lane = tid & 63, w = tid >> 6;

    // reduce part over kc -> features X[z*128 + j2]
    #pragma unroll
    for (int i = 0; i < 8; i++){
        int idx = tid + i*256; int z = idx >> 7, j2 = idx & 127;
        const unsigned short* p = part + ((size_t)(z*NKC)*NATOMS + a)*128 + j2;
        float s = 0.f;
        #pragma unroll
        for (int c = 0; c < NKC; c++) s += bf2f(p[(size_t)c*NATOMS*128]);
        X[idx] = spf_act(s) * mask[z*NATOMS + a];
    }
    __syncthreads();
    // h1
    f32x4 v[2]; float s = 0.f, ss = 0.f;
    #pragma unroll
    for (int i = 0; i < 2; i++){
        int idx4 = tid + i*256; int z = idx4 >> 5, k4 = (idx4 & 31)*4;
        f32x4 acc = { fb1[k4], fb1[k4+1], fb1[k4+2], fb1[k4+3] };
        #pragma unroll 4
        for (int c = 0; c < 128; c++){
            float xv = X[z*128 + c];
            float4 wv = *(const float4*)(fW1 + (size_t)c*128 + k4);
            acc[0] += xv*wv.x; acc[1] += xv*wv.y; acc[2] += xv*wv.z; acc[3] += xv*wv.w;
        }
        v[i] = acc;
        s += acc[0]+acc[1]+acc[2]+acc[3];
        ss += acc[0]*acc[0]+acc[1]*acc[1]+acc[2]*acc[2]+acc[3]*acc[3];
    }
    for (int off = 32; off; off >>= 1){ s += __shfl_down(s, off); ss += __shfl_down(ss, off); }
    if (!lane){ red[w] = s; red[8+w] = ss; }
    __syncthreads();
    if (!tid){
        float S = red[0]+red[1]+red[2]+red[3];
        float SS = red[8]+red[9]+red[10]+red[11];
        float m = S*(1.f/2048.f), var = SS*(1.f/2048.f) - m*m;
        stats[0] = m; stats[1] = rsqrtf(var + 1e-5f);
    }
    __syncthreads();
    float m1 = stats[0], inv1 = stats[1];
    #pragma unroll
    for (int i = 0; i < 2; i++){
        int idx4 = tid + i*256;
        f32x4 t;
        #pragma unroll
        for (int e = 0; e < 4; e++){
            float x = (v[i][e]-m1)*inv1;
            t[e] = (x > 0.f) ? x : 0.2f*x;
        }
        *(f32x4*)(X + idx4*4) = t;
    }
    __syncthreads();
    // h2
    float u[2]; s = 0.f; ss = 0.f;
    #pragma unroll
    for (int i = 0; i < 2; i++){
        int idx = tid + i*256; int z = idx >> 5, j = idx & 31;
        float acc = fb2[j];
        #pragma unroll 8
        for (int k = 0; k < 128; k++) acc += X[z*128 + k]*fW2[k*32 + j];
        u[i] = acc; s += acc; ss += acc*acc;
    }
    for (int off = 32; off; off >>= 1){ s += __shfl_down(s, off); ss += __shfl_down(ss, off); }
    if (!lane){ red[w] = s; red[8+w] = ss; }
    __syncthreads();
    if (!tid){
        float S = red[0]+red[1]+red[2]+red[3];
        float SS = red[8]+red[9]+red[10]+red[11];
        float m = S*(1.f/512.f), var = SS*(1.f/512.f) - m*m;
        stats[0] = m; stats[1] = rsqrtf(var + 1e-5f);
    }
    __syncthreads();
    float m2 = stats[0], inv2 = stats[1];
    #pragma unroll
    for (int i = 0; i < 2; i++){
        int idx = tid + i*256; int z = idx >> 5, j = idx & 31;
        float x = (u[i]-m2)*inv2;
        x = (x > 0.f) ? x : 0.2f*x;
        x *= mask[z*NATOMS + a];
        atomicAdd(&out[z*32 + j], x);
    }
}

extern "C" void kernel_launch(void* const* d_in, const int* in_sizes, int n_in,
                              void* d_out, int out_size, void* d_ws, size_t ws_size,
                              hipStream_t stream){
    const float* features = (const float*)d_in[0];
    const float* geometry = (const float*)d_in[1];
    const float* mask     = (const float*)d_in[2];
    const float* W_bio    = (const float*)d_in[3];
    const float* b_bio    = (const float*)d_in[4];
    const float* W_ch     = (const float*)d_in[5];
    const float* b_ch     = (const float*)d_in[6];
    const float* rW1[2] = {(const float*)d_in[7],  (const float*)d_in[12]};
    const float* rb1[2] = {(const float*)d_in[8],  (const float*)d_in[13]};
    const float* rW2[2] = {(const float*)d_in[9],  (const float*)d_in[14]};
    const float* rb2[2] = {(const float*)d_in[10], (const float*)d_in[15]};
    const float* rWo[2] = {(const float*)d_in[11], (const float*)d_in[16]};
    const float* fW1 = (const float*)d_in[17];
    const float* fb1 = (const float*)d_in[18];
    const float* fW2 = (const float*)d_in[19];
    const float* fb2 = (const float*)d_in[20];

    char* ws = (char*)d_ws;
    unsigned short* fAb = (unsigned short*)ws;   ws += (size_t)ZA*64*2;
    unsigned short* fAc = (unsigned short*)ws;   ws += (size_t)ZA*64*2;
    unsigned short* w2T = (unsigned short*)ws;   ws += (size_t)2*4096*2;
    unsigned short* Bp = (unsigned short*)ws;    ws += (size_t)2*262144*2;           // 1 MB
    unsigned short* Tg = (unsigned short*)ws;    ws += (size_t)ZA*8192*2;            // 50.3 MB
    unsigned short* part = (unsigned short*)ws;  ws += (size_t)ZB*NKC*NATOMS*128*2;   // 37.7 MB

    hipMemsetAsync(d_out, 0, (size_t)out_size*sizeof(float), stream);

    dim3 gt(24, 32, 2);
    dim3 gf(ZB, NKC);
    dim3 gd(96, ZB);
    // one prep launch: both layers' w2T + Bp
    k_prep<<<512, 256, 0, stream>>>(rW2[0], rW2[1], rWo[0], rWo[1], w2T, Bp);
    // layer 0 (encode fused into tmpB)
    k_tmpB<<<gt, 256, 0, stream>>>(nullptr, nullptr, features, W_bio, b_bio, W_ch, b_ch,
                                   mask, Bp, Tg);
    k_fused<<<gf, 256, 0, stream>>>(geometry, rW1[0], rb1[0], w2T, rb2[0], Tg, part);
    k_reduceB<<<gd, 256, 0, stream>>>(part, mask, fAb, fAc);
    // layer 1
    k_tmpB<<<gt, 256, 0, stream>>>(fAb, fAc, nullptr, W_bio, b_bio, W_ch, b_ch,
                                   mask, Bp + 262144, Tg);
    k_fused<<<gf, 256, 0, stream>>>(geometry, rW1[1], rb1[1], w2T + 4096, rb2[1], Tg, part);
    // fused tail: reduce(layer1) + head + sum (atomics into zeroed out)
    k_head2<<<NATOMS, 256, 0, stream>>>(part, mask, fW1, fb1, fW2, fb2, (float*)d_out);
}

// Round 15
// 249.159 us; speedup vs baseline: 1.5282x; 1.5282x over previous
//
#include <hip/hip_runtime.h>
#include <math.h>

#define ZB 16
#define NATOMS 192
#define NBAS 40
#define ZA (ZB*NATOMS)       // 3072
#define NKC 32               // K-chunks in contraction

typedef __attribute__((ext_vector_type(4))) float f32x4;
typedef __attribute__((ext_vector_type(8))) short bf16x8;

__device__ __forceinline__ unsigned short f2bf(float x){
    union { float f; unsigned u; } v; v.f = x;
    unsigned r = v.u + 0x7FFFu + ((v.u >> 16) & 1u);
    return (unsigned short)(r >> 16);
}
// truncating bf16 (1 op) — hot paths
__device__ __forceinline__ unsigned short f2bf_t(float x){
    union { float f; unsigned u; } v; v.f = x;
    return (unsigned short)(v.u >> 16);
}
__device__ __forceinline__ float bf2f(unsigned short u){
    union { unsigned u; float f; } v; v.u = ((unsigned)u) << 16; return v.f;
}
__device__ __forceinline__ float bits2f(unsigned u){
    union { unsigned u; float f; } v; v.u = u; return v.f;
}
__device__ __forceinline__ unsigned f2bits(float x){
    union { float f; unsigned u; } v; v.f = x; return v.u;
}
// lean ssp: inputs bounded (|x| << 17) so no overflow guard needed
__device__ __forceinline__ float sspf_lean(float x){
    float e = __builtin_amdgcn_exp2f(7.2134752f*x);
    float l = __builtin_amdgcn_logf(1.f + e);
    return fmaf(l, 0.13862944f, -0.13862944f);
}
__device__ __forceinline__ float spf_act(float x){
    float t = 7.2134752f*x;
    float tc = fminf(t, 126.f);
    float e = __builtin_amdgcn_exp2f(tc);
    float l = __builtin_amdgcn_logf(1.f + e);
    float r = l*0.13862944f;
    return (t > 126.f) ? x : r;
}

// ---------------- prep: w2T[layer][hout*64+hin] = bf16(rW2[hin][hout]) and
// Bp[layer][(j*64+h)*64 + i] = bf16(rWo[h][j][i]) — both layers, one launch
__global__ void k_prep(const float* __restrict__ rW2_0, const float* __restrict__ rW2_1,
                       const float* __restrict__ rWo_0, const float* __restrict__ rWo_1,
                       unsigned short* __restrict__ w2T, unsigned short* __restrict__ Bp){
    int idx = blockIdx.x*256 + threadIdx.x;
    if (idx < 8192){
        int l = idx >> 12, r = idx & 4095;
        int hout = r >> 6, hin = r & 63;
        const float* src = l ? rW2_1 : rW2_0;
        w2T[idx] = f2bf(src[hin*64 + hout]);
    }
    for (int i = idx; i < 2*262144; i += gridDim.x*256){
        int l = i >> 18, r = i & 262143;
        int n = r >> 6, ii = r & 63;       // n = j*64+h
        int j = n >> 6, h = n & 63;
        const float* src = l ? rWo_1 : rWo_0;
        Bp[i] = f2bf(src[(h*64 + j)*64 + ii]);
    }
}

// ---------------- tmp GEMM bf16 MFMA: Tg[m][s*4096 + j*64 + h] = (f_s[m] @ rWo[h][j][:]) * mask*c
// layer 0 (feat != null): f_s rows computed on the fly from the linear encoders.
__global__ __launch_bounds__(256,2) void k_tmpB(
    const unsigned short* __restrict__ fb, const unsigned short* __restrict__ fc,
    const float* __restrict__ feat,
    const float* __restrict__ Wb, const float* __restrict__ bb,
    const float* __restrict__ Wc, const float* __restrict__ bc,
    const float* __restrict__ mask, const unsigned short* __restrict__ Bp,
    unsigned short* __restrict__ Tg)
{
    __shared__ unsigned short sm[18432];   // As[128*72] | Bs[128*72]; Cs overlays all
    __shared__ float msk[128];
    __shared__ float featS[128*8];
    __shared__ float WbS[7*64];
    __shared__ float bbS[64], WcS[64], bcS[64];
    unsigned short* As = sm;
    unsigned short* Bs = sm + 9216;
    unsigned short* Cs = sm;

    int tid = threadIdx.x;
    int m0 = blockIdx.x*128, n0 = blockIdx.y*128, s = blockIdx.z;
    int lane = tid & 63, w = tid >> 6, q = lane >> 4, l15 = lane & 15;
    int wm = w & 1, wn = w >> 1;

    if (feat){
        #pragma unroll
        for (int it = 0; it < 4; it++){
            int idx = tid + it*256;            // 1024 floats
            featS[idx] = feat[(size_t)m0*8 + idx];
        }
        for (int i = tid; i < 448; i += 256) WbS[i] = Wb[i];   // 7x64, strided
        if (tid < 64){ bbS[tid] = bb[tid]; WcS[tid] = Wc[tid]; bcS[tid] = bc[tid]; }
        __syncthreads();
        #pragma unroll
        for (int it = 0; it < 32; it++){
            int idx = tid + it*256;            // 8192
            int r = idx >> 6, e = idx & 63;
            float acc;
            if (s == 0){
                acc = bbS[e];
                #pragma unroll
                for (int c = 0; c < 7; c++) acc += featS[r*8+c]*WbS[c*64+e];
            } else {
                acc = bcS[e] + featS[r*8+7]*WcS[e];
            }
            As[r*72 + e] = f2bf(acc);
        }
    } else {
        const unsigned short* f = s ? fc : fb;
        #pragma unroll
        for (int it = 0; it < 4; it++){
            int idx = tid + it*256;            // 1024 uint4
            int r = idx >> 3, c8 = idx & 7;
            *(uint4*)(As + r*72 + c8*8) = *(const uint4*)(f + (size_t)(m0 + r)*64 + c8*8);
        }
    }
    // B-staging: pure uint4 copies from pre-converted Bp rows
    #pragma unroll
    for (int it = 0; it < 4; it++){
        int idx = tid + it*256;                // 1024 uint4
        int r = idx >> 3, c8 = idx & 7;
        *(uint4*)(Bs + r*72 + c8*8) = *(const uint4*)(Bp + (size_t)(n0 + r)*64 + c8*8);
    }
    if (tid < 128) msk[tid] = mask[m0 + tid] * 0.07216878364870322f;
    __syncthreads();

    f32x4 acc[16];
    #pragma unroll
    for (int i = 0; i < 16; i++) acc[i] = (f32x4){0.f,0.f,0.f,0.f};
    #pragma unroll
    for (int kc = 0; kc < 2; kc++){
        bf16x8 af[4];
        #pragma unroll
        for (int mt = 0; mt < 4; mt++)
            af[mt] = *(const bf16x8*)(As + (wm*64 + mt*16 + l15)*72 + kc*32 + q*8);
        #pragma unroll
        for (int nt = 0; nt < 4; nt++){
            bf16x8 bf_ = *(const bf16x8*)(Bs + (wn*64 + nt*16 + l15)*72 + kc*32 + q*8);
            #pragma unroll
            for (int mt = 0; mt < 4; mt++)
                acc[mt*4+nt] = __builtin_amdgcn_mfma_f32_16x16x32_bf16(af[mt], bf_, acc[mt*4+nt], 0, 0, 0);
        }
    }
    __syncthreads();   // all As/Bs reads done -> overlay Cs
    #pragma unroll
    for (int mt = 0; mt < 4; mt++)
        #pragma unroll
        for (int nt = 0; nt < 4; nt++)
            #pragma unroll
            for (int e = 0; e < 4; e++){
                int row2 = mt*16 + q*4 + e;
                float v = acc[mt*4+nt][e] * msk[wm*64 + row2];
                Cs[w*4608 + row2*72 + nt*16 + l15] = f2bf_t(v);
            }
    __syncthreads();
    #pragma unroll
    for (int it = 0; it < 8; it++){
        int flat = lane + it*64;               // [0,512)
        int rr = flat >> 3, c8 = flat & 7;
        uint4 v = *(const uint4*)(Cs + w*4608 + rr*72 + c8*8);
        size_t dst = (size_t)(m0 + wm*64 + rr)*8192 + s*4096 + n0 + wn*64 + c8*8;
        *(uint4*)(Tg + dst) = v;
    }
}

// ---------------- FUSED radial + contraction. Grid (ZB, NKC=32), 6 b's per block.
// Round-13 config: double-buffered smB, launch_bounds(256,2) — register-capped at
// 2 waves/SIMD (96 acc-AGPR + ~124 VGPR); (256,3) spills acc to scratch (round 14).
__global__ __launch_bounds__(256,2) void k_fused(
    const float* __restrict__ geom,
    const float* __restrict__ rW1, const float* __restrict__ rb1,
    const unsigned short* __restrict__ w2T, const float* __restrict__ rb2,
    const unsigned short* __restrict__ Tc,
    unsigned short* __restrict__ part)
{
    __shared__ unsigned short smH[192*72];      // 27648 B: R tile -> epilogue staging
    __shared__ unsigned short smB[2][128*72];   // 36864 B: Tg tile double buffer
    __shared__ unsigned short W1bf[NBAS*72];    // 5760 B, rows padded to 72
    __shared__ float rb2s[64];

    int tid = threadIdx.x;
    int z = blockIdx.x, kc = blockIdx.y;
    int lane = tid & 63, w = tid >> 6, q = lane >> 4, l15 = lane & 15;
    int a_r = tid >> 3, c8 = tid & 7;

    #pragma unroll
    for (int i = 0; i < 10; i++){
        int idx = tid + i*256;                 // [0,2560)
        int r = idx >> 6, c = idx & 63;
        W1bf[r*72 + c] = f2bf(rW1[idx]);
    }
    if (tid < 64) rb2s[tid] = rb2[tid];

    bf16x8 bfr[2][4];
    #pragma unroll
    for (int kq = 0; kq < 2; kq++)
        #pragma unroll
        for (int nt = 0; nt < 4; nt++)
            bfr[kq][nt] = *(const bf16x8*)(w2T + (nt*16 + l15)*64 + kq*32 + q*8);

    float rb1v[2][8];
    #pragma unroll
    for (int kq = 0; kq < 2; kq++){
        float4 t0 = *(const float4*)(rb1 + kq*32 + q*8);
        float4 t1 = *(const float4*)(rb1 + kq*32 + q*8 + 4);
        rb1v[kq][0]=t0.x; rb1v[kq][1]=t0.y; rb1v[kq][2]=t0.z; rb1v[kq][3]=t0.w;
        rb1v[kq][4]=t1.x; rb1v[kq][5]=t1.y; rb1v[kq][6]=t1.z; rb1v[kq][7]=t1.w;
    }

    float gaxr[3], gayr[3], gazr[3];
    #pragma unroll
    for (int mt = 0; mt < 3; mt++){
        int ar = w*48 + mt*16 + l15;
        const float* gp = geom + (size_t)(z*NATOMS + ar)*3;
        gaxr[mt] = gp[0]; gayr[mt] = gp[1]; gazr[mt] = gp[2];
    }

    const size_t Tbase = (size_t)z*NATOMS*8192;
    uint4 rbv[4];
    {
        const unsigned short* Bb = Tc + Tbase + (size_t)(kc*6)*8192;
        #pragma unroll
        for (int r = 0; r < 4; r++) rbv[r] = *(const uint4*)(Bb + (size_t)(a_r + 32*r)*64 + c8*8);
    }

    f32x4 acc[24];
    #pragma unroll
    for (int i = 0; i < 24; i++) acc[i] = (f32x4){0.f,0.f,0.f,0.f};

    __syncthreads();           // W1bf / rb2s staged

    for (int i = 0; i < 6; i++){
        int buf = i & 1;
        int b = kc*6 + i;
        #pragma unroll
        for (int r = 0; r < 4; r++) *(uint4*)(smB[buf] + (a_r + 32*r)*72 + c8*8) = rbv[r];
        if (i < 5){
            const unsigned short* Bb = Tc + Tbase + (size_t)(b+1)*8192;
            #pragma unroll
            for (int r = 0; r < 4; r++) rbv[r] = *(const uint4*)(Bb + (size_t)(a_r + 32*r)*64 + c8*8);
        }
        const float* gb = geom + (size_t)(z*NATOMS + b)*3;
        float gbx = gb[0], gby = gb[1], gbz = gb[2];
        float c0r[3], c1r[3]; int o0r[3], o1r[3];
        #pragma unroll
        for (int mt = 0; mt < 3; mt++){
            float dx = gaxr[mt]-gbx, dy = gayr[mt]-gby, dz = gazr[mt]-gbz;
            float r = sqrtf(dx*dx + dy*dy + dz*dz);
            float u = r * 3.9f;
            int k0 = (int)u;
            float fr = u - (float)k0;
            float cs = __cosf(fr * 1.57079632679489662f);
            float c0 = cs*cs, c1 = 1.f - c0;
            if (k0   >= NBAS) c0 = 0.f;
            if (k0+1 >= NBAS) c1 = 0.f;
            c0r[mt] = c0; c1r[mt] = c1;
            o0r[mt] = min(k0, NBAS-1)*72;
            o1r[mt] = min(k0+1, NBAS-1)*72;
        }
        __syncthreads();       // smB[buf] visible to all waves
        f32x4 hacc[12];
        #pragma unroll
        for (int t = 0; t < 12; t++) hacc[t] = (f32x4){0.f,0.f,0.f,0.f};
        #pragma unroll
        for (int kq = 0; kq < 2; kq++){
            #pragma unroll
            for (int mt = 0; mt < 3; mt++){
                uint4 w0 = *(const uint4*)(W1bf + o0r[mt] + kq*32 + q*8);
                uint4 w1 = *(const uint4*)(W1bf + o1r[mt] + kq*32 + q*8);
                const unsigned* w0p = (const unsigned*)&w0;
                const unsigned* w1p = (const unsigned*)&w1;
                uint4 af_u;
                unsigned* ap = (unsigned*)&af_u;
                #pragma unroll
                for (int d = 0; d < 4; d++){
                    float a0 = bits2f(w0p[d] << 16);
                    float a1 = bits2f(w0p[d] & 0xffff0000u);
                    float b0 = bits2f(w1p[d] << 16);
                    float b1 = bits2f(w1p[d] & 0xffff0000u);
                    float v0 = fmaf(c1r[mt], b0, fmaf(c0r[mt], a0, rb1v[kq][2*d]));
                    float v1 = fmaf(c1r[mt], b1, fmaf(c0r[mt], a1, rb1v[kq][2*d+1]));
                    unsigned u0 = f2bits(sspf_lean(v0));
                    unsigned u1 = f2bits(sspf_lean(v1));
                    ap[d] = (u0 >> 16) | (u1 & 0xffff0000u);
                }
                bf16x8 af = *(bf16x8*)&af_u;
                #pragma unroll
                for (int nt = 0; nt < 4; nt++)
                    hacc[mt*4+nt] = __builtin_amdgcn_mfma_f32_16x16x32_bf16(af, bfr[kq][nt], hacc[mt*4+nt], 0, 0, 0);
            }
        }
        #pragma unroll
        for (int mt = 0; mt < 3; mt++)
            #pragma unroll
            for (int nt = 0; nt < 4; nt++){
                float b2 = rb2s[nt*16 + l15];
                #pragma unroll
                for (int e = 0; e < 4; e++){
                    int row = w*48 + mt*16 + q*4 + e;
                    smH[row*72 + nt*16 + l15] = f2bf_t(sspf_lean(hacc[mt*4+nt][e] + b2));
                }
            }
        #pragma unroll
        for (int kq = 0; kq < 2; kq++){
            bf16x8 af[3];
            #pragma unroll
            for (int mt = 0; mt < 3; mt++)
                af[mt] = *(const bf16x8*)(smH + (w*48 + mt*16 + l15)*72 + kq*32 + q*8);
            #pragma unroll
            for (int nt = 0; nt < 8; nt++){
                bf16x8 bb = *(const bf16x8*)(smB[buf] + (nt*16 + l15)*72 + kq*32 + q*8);
                #pragma unroll
                for (int mt = 0; mt < 3; mt++)
                    acc[mt*8+nt] = __builtin_amdgcn_mfma_f32_16x16x32_bf16(af[mt], bb, acc[mt*8+nt], 0, 0, 0);
            }
        }
    }
    // epilogue: LDS-staged contiguous write of part tile (192x128 bf16)
    unsigned short* stg = smH;               // row stride 136 shorts
    #pragma unroll
    for (int half = 0; half < 2; half++){
        __syncthreads();
        if ((w >> 1) == half){
            int wl = w & 1;
            #pragma unroll
            for (int mt = 0; mt < 3; mt++)
                #pragma unroll
                for (int nt = 0; nt < 8; nt++)
                    #pragma unroll
                    for (int e = 0; e < 4; e++){
                        int row = wl*48 + mt*16 + q*4 + e;      // [0,96)
                        stg[row*136 + nt*16 + l15] = f2bf_t(acc[mt*8+nt][e]);
                    }
        }
        __syncthreads();
        unsigned short* gdst = part + ((size_t)(z*NKC + kc)*NATOMS + half*96)*128;
        #pragma unroll
        for (int it = 0; it < 6; it++){
            int flat = tid + it*256;          // [0,1536) uint4s
            int row = flat >> 4, cc = flat & 15;
            uint4 v = *(const uint4*)(stg + row*136 + cc*8);
            *(uint4*)(gdst + row*128 + cc*8) = v;
        }
    }
}

// ---------------- reduce partials + sp + mask -> bf16 next features (layer 0 only)
__global__ void k_reduceB(const unsigned short* __restrict__ part, const float* __restrict__ mask,
                          unsigned short* __restrict__ fb, unsigned short* __restrict__ fc){
    int zl = blockIdx.y;
    int idx = blockIdx.x*256 + threadIdx.x;    // [0, 24576)
    int a = idx >> 7, j2 = idx & 127;
    const unsigned short* p = part + ((size_t)(zl*NKC)*NATOMS + a)*128 + j2;
    float s = 0.f;
    #pragma unroll
    for (int c = 0; c < NKC; c++) s += bf2f(p[(size_t)c*NATOMS*128]);
    int rowg = zl*NATOMS + a;
    float v = spf_act(s) * mask[rowg];
    if (j2 < 64) fb[rowg*64 + j2] = f2bf(v);
    else         fc[rowg*64 + j2 - 64] = f2bf(v);
}

// ---------------- fused tail: reduce(layer1) + sp + mask + h1 + BN1 + leaky + h2 + BN2
// + leaky + mask + atom-sum (atomicAdd into zeroed out). One block per atom, 512 thr.
__global__ __launch_bounds__(512) void k_head2(
    const unsigned short* __restrict__ part, const float* __restrict__ mask,
    const float* __restrict__ fW1, const float* __restrict__ fb1,
    const float* __restrict__ fW2, const float* __restrict__ fb2,
    float* __restrict__ out)
{
    __shared__ float X[2048];
    __shared__ float red[16];
    __shared__ float stats[2];
    int a = blockIdx.x, tid = threadIdx.x;     // 512 threads = 8 waves
    int lane = tid & 63, w = tid >> 6;

    // reduce part over kc -> features X[z*128 + j2]
    #pragma unroll
    for (int i = 0; i < 4; i++){
        int idx = tid + i*512; int z = idx >> 7, j2 = idx & 127;
        const unsigned short* p = part + ((size_t)(z*NKC)*NATOMS + a)*128 + j2;
        float s = 0.f;
        #pragma unroll
        for (int c = 0; c < NKC; c++) s += bf2f(p[(size_t)c*NATOMS*128]);
        X[idx] = spf_act(s) * mask[z*NATOMS + a];
    }
    __syncthreads();
    // h1: one float4 output per thread (512 x 4 = 2048)
    f32x4 v; float s, ss;
    {
        int z = tid >> 5, k4 = (tid & 31)*4;
        f32x4 acc = { fb1[k4], fb1[k4+1], fb1[k4+2], fb1[k4+3] };
        #pragma unroll 4
        for (int c = 0; c < 128; c++){
            float xv = X[z*128 + c];
            float4 wv = *(const float4*)(fW1 + (size_t)c*128 + k4);
            acc[0] += xv*wv.x; acc[1] += xv*wv.y; acc[2] += xv*wv.z; acc[3] += xv*wv.w;
        }
        v = acc;
        s = acc[0]+acc[1]+acc[2]+acc[3];
        ss = acc[0]*acc[0]+acc[1]*acc[1]+acc[2]*acc[2]+acc[3]*acc[3];
    }
    for (int off = 32; off; off >>= 1){ s += __shfl_down(s, off); ss += __shfl_down(ss, off); }
    if (!lane){ red[w] = s; red[8+w] = ss; }
    __syncthreads();
    if (!tid){
        float S = 0.f, SS = 0.f;
        #pragma unroll
        for (int i = 0; i < 8; i++){ S += red[i]; SS += red[8+i]; }
        float m = S*(1.f/2048.f), var = SS*(1.f/2048.f) - m*m;
        stats[0] = m; stats[1] = rsqrtf(var + 1e-5f);
    }
    __syncthreads();
    float m1 = stats[0], inv1 = stats[1];
    {
        f32x4 t;
        #pragma unroll
        for (int e = 0; e < 4; e++){
            float x = (v[e]-m1)*inv1;
            t[e] = (x > 0.f) ? x : 0.2f*x;
        }
        *(f32x4*)(X + tid*4) = t;
    }
    __syncthreads();
    // h2: one output per thread (512)
    float u; 
    {
        int z = tid >> 5, j = tid & 31;
        float acc = fb2[j];
        #pragma unroll 8
        for (int k = 0; k < 128; k++) acc += X[z*128 + k]*fW2[k*32 + j];
        u = acc; s = acc; ss = acc*acc;
    }
    for (int off = 32; off; off >>= 1){ s += __shfl_down(s, off); ss += __shfl_down(ss, off); }
    if (!lane){ red[w] = s; red[8+w] = ss; }
    __syncthreads();
    if (!tid){
        float S = 0.f, SS = 0.f;
        #pragma unroll
        for (int i = 0; i < 8; i++){ S += red[i]; SS += red[8+i]; }
        float m = S*(1.f/512.f), var = SS*(1.f/512.f) - m*m;
        stats[0] = m; stats[1] = rsqrtf(var + 1e-5f);
    }
    __syncthreads();
    float m2 = stats[0], inv2 = stats[1];
    {
        int z = tid >> 5, j = tid & 31;
        float x = (u-m2)*inv2;
        x = (x > 0.f) ? x : 0.2f*x;
        x *= mask[z*NATOMS + a];
        atomicAdd(&out[z*32 + j], x);
    }
}

extern "C" void kernel_launch(void* const* d_in, const int* in_sizes, int n_in,
                              void* d_out, int out_size, void* d_ws, size_t ws_size,
                              hipStream_t stream){
    const float* features = (const float*)d_in[0];
    const float* geometry = (const float*)d_in[1];
    const float* mask     = (const float*)d_in[2];
    const float* W_bio    = (const float*)d_in[3];
    const float* b_bio    = (const float*)d_in[4];
    const float* W_ch     = (const float*)d_in[5];
    const float* b_ch     = (const float*)d_in[6];
    const float* rW1[2] = {(const float*)d_in[7],  (const float*)d_in[12]};
    const float* rb1[2] = {(const float*)d_in[8],  (const float*)d_in[13]};
    const float* rW2[2] = {(const float*)d_in[9],  (const float*)d_in[14]};
    const float* rb2[2] = {(const float*)d_in[10], (const float*)d_in[15]};
    const float* rWo[2] = {(const float*)d_in[11], (const float*)d_in[16]};
    const float* fW1 = (const float*)d_in[17];
    const float* fb1 = (const float*)d_in[18];
    const float* fW2 = (const float*)d_in[19];
    const float* fb2 = (const float*)d_in[20];

    char* ws = (char*)d_ws;
    unsigned short* fAb = (unsigned short*)ws;   ws += (size_t)ZA*64*2;
    unsigned short* fAc = (unsigned short*)ws;   ws += (size_t)ZA*64*2;
    unsigned short* w2T = (unsigned short*)ws;   ws += (size_t)2*4096*2;
    unsigned short* Bp = (unsigned short*)ws;    ws += (size_t)2*262144*2;           // 1 MB
    unsigned short* Tg = (unsigned short*)ws;    ws += (size_t)ZA*8192*2;            // 50.3 MB
    unsigned short* part = (unsigned short*)ws;  ws += (size_t)ZB*NKC*NATOMS*128*2;   // 25.2 MB

    hipMemsetAsync(d_out, 0, (size_t)out_size*sizeof(float), stream);

    dim3 gt(24, 32, 2);
    dim3 gf(ZB, NKC);
    dim3 gd(96, ZB);
    // one prep launch: both layers' w2T + Bp
    k_prep<<<512, 256, 0, stream>>>(rW2[0], rW2[1], rWo[0], rWo[1], w2T, Bp);
    // layer 0 (encode fused into tmpB)
    k_tmpB<<<gt, 256, 0, stream>>>(nullptr, nullptr, features, W_bio, b_bio, W_ch, b_ch,
                                   mask, Bp, Tg);
    k_fused<<<gf, 256, 0, stream>>>(geometry, rW1[0], rb1[0], w2T, rb2[0], Tg, part);
    k_reduceB<<<gd, 256, 0, stream>>>(part, mask, fAb, fAc);
    // layer 1
    k_tmpB<<<gt, 256, 0, stream>>>(fAb, fAc, nullptr, W_bio, b_bio, W_ch, b_ch,
                                   mask, Bp + 262144, Tg);
    k_fused<<<gf, 256, 0, stream>>>(geometry, rW1[1], rb1[1], w2T + 4096, rb2[1], Tg, part);
    // fused tail: reduce(layer1) + head + sum (atomics into zeroed out)
    k_head2<<<NATOMS, 512, 0, stream>>>(part, mask, fW1, fb1, fW2, fb2, (float*)d_out);
}